// Round 13
// baseline (195.788 us; speedup 1.0000x reference)
//
#include <hip/hip_runtime.h>
#include <math.h>

#define NHID 512
#define T_K  256
#define T_Q  128
#define BB   8

// MEASUREMENT ROUND: hot loops repeated REP x (results scaled back).
#define REP 4

// tanh(x) = 1 - 2/(exp2(C*x)+1), C = 2*log2(e)
constexpr float C2L2E = 2.8853900817779268f;
constexpr float L2E   = 1.4426950408889634f;

__device__ __forceinline__ float fexp2(float x) { return __builtin_amdgcn_exp2f(x); }
__device__ __forceinline__ float frcp(float x)  { return __builtin_amdgcn_rcpf(x); }

typedef __attribute__((ext_vector_type(8))) short bf16x8;
typedef __attribute__((ext_vector_type(4))) float f32x4;

__device__ __forceinline__ unsigned short f2bf(float x) {
    unsigned u = __builtin_bit_cast(unsigned, x);
    unsigned r = (u + 0x7FFFu + ((u >> 16) & 1u)) >> 16;
    return (unsigned short)r;
}
__device__ __forceinline__ float bf2f(unsigned short h) {
    unsigned u = ((unsigned)h) << 16;
    return __builtin_bit_cast(float, u);
}
__device__ __forceinline__ unsigned packbf(float a, float b) {
    return (unsigned)f2bf(a) | ((unsigned)f2bf(b) << 16);
}

// ---------------------------------------------------------------------------
// Kernel 0: blocks 0..127: W1 -> BT_hi/lo. blocks 128..383: ckey -> ckp.
// (unchanged)
// ---------------------------------------------------------------------------
__global__ __launch_bounds__(256) void convert_kernel(
    const float* __restrict__ W1, const float* __restrict__ ckey,
    unsigned short* __restrict__ bt_hi, unsigned short* __restrict__ bt_lo,
    unsigned int* __restrict__ ckp)
{
    const int bid = blockIdx.x;
    const int t   = threadIdx.x;
    if (bid < 128) {
        const int kt = bid & 15;
        const int nt = bid >> 4;
        __shared__ float tile[64][65];
        const int r  = t >> 2;
        const int c0 = (t & 3) * 16;
        const float* src = W1 + (size_t)(kt * 64 + r) * 512 + nt * 64 + c0;
        #pragma unroll
        for (int j = 0; j < 4; ++j) {
            const float4 v = *(const float4*)&src[j * 4];
            tile[r][c0 + j * 4 + 0] = v.x; tile[r][c0 + j * 4 + 1] = v.y;
            tile[r][c0 + j * 4 + 2] = v.z; tile[r][c0 + j * 4 + 3] = v.w;
        }
        __syncthreads();
        const size_t dst = (size_t)((kt >> 3) * 512 + nt * 64 + r) * 512
                         + (size_t)((kt & 7) * 64 + c0);
        #pragma unroll
        for (int j4 = 0; j4 < 4; ++j4) {
            ushort4 h, l;
            #pragma unroll
            for (int e = 0; e < 4; ++e) {
                const float x = tile[c0 + j4 * 4 + e][r];
                const unsigned short hb = f2bf(x);
                ((unsigned short*)&h)[e] = hb;
                ((unsigned short*)&l)[e] = f2bf(x - bf2f(hb));
            }
            *(ushort4*)&bt_hi[dst + j4 * 4] = h;
            *(ushort4*)&bt_lo[dst + j4 * 4] = l;
        }
    } else {
        const int cb = bid - 128;      // 0..255
        const int b  = cb >> 5;        // 0..7
        const int kt = cb & 31;        // 0..31
        const int kloc = t >> 5;       // 0..7
        const int g    = t & 31;       // 0..31
        const int k = kt * 8 + kloc;
        const float* src = ckey + ((size_t)k * 8 + b) * 512 + g * 16;
        const float4 v0 = *(const float4*)&src[0];
        const float4 v1 = *(const float4*)&src[4];
        const float4 v2 = *(const float4*)&src[8];
        const float4 v3 = *(const float4*)&src[12];
        uint4 o0, o1;
        o0.x = packbf(v0.x, v0.y); o0.y = packbf(v0.z, v0.w);
        o0.z = packbf(v1.x, v1.y); o0.w = packbf(v1.z, v1.w);
        o1.x = packbf(v2.x, v2.y); o1.y = packbf(v2.z, v2.w);
        o1.z = packbf(v3.x, v3.y); o1.w = packbf(v3.z, v3.w);
        unsigned int* dst = ckp + ((size_t)b * 256 + k) * 256 + g * 8;
        *(uint4*)&dst[0] = o0;
        *(uint4*)&dst[4] = o1;
    }
}

// ---------------------------------------------------------------------------
// Kernel 1: proj GEMM (R12 structure) with k-loop repeated REP x.
// acc accumulates across repeats; epilogue scales by 1/REP. Each repeat
// re-stages LDS through barriers -> compiler cannot CSE.
// ---------------------------------------------------------------------------
__global__ __launch_bounds__(256) void proj_kernel(
    const float* __restrict__ qry, const float* __restrict__ ckey,
    const unsigned short* __restrict__ bt_hi, const unsigned short* __restrict__ bt_lo,
    const float* __restrict__ b1,
    uint2* __restrict__ ektq, float* __restrict__ eq)
{
    const int row0 = blockIdx.x * 32;   // 96 tiles
    const int col0 = blockIdx.y * 64;   // 8 tiles
    const bool isK = row0 < 2048;
    const int bhalf = isK ? 0 : 512;

    __shared__ __align__(16) unsigned short As_h[32 * 64];
    __shared__ __align__(16) unsigned short As_l[32 * 64];
    __shared__ __align__(16) unsigned short Bs_h[64 * 64];
    __shared__ __align__(16) unsigned short Bs_l[64 * 64];

    const int t    = threadIdx.x;
    const int wave = t >> 6;
    const int lane = t & 63;
    const int wm = (wave & 1) * 16;
    const int wn = (wave >> 1) * 32;

    f32x4 acc[2] = {};

    const int srA = t >> 3;
    const int scA = (t & 7) * 8;
    const float* gA = (isK ? ckey + (size_t)(row0 + srA) * 512
                           : qry  + (size_t)(row0 - 2048 + srA) * 512) + scA;
    const int swA = ((scA >> 3) ^ (srA & 7)) * 8;

    const int srB = t >> 2;
    const int scB = (t & 3) * 16;
    const unsigned short* gBh = bt_hi + (size_t)(bhalf + col0 + srB) * 512 + scB;
    const unsigned short* gBl = bt_lo + (size_t)(bhalf + col0 + srB) * 512 + scB;
    const int cB = scB >> 3;
    const int swB0 = ((cB + 0) ^ (srB & 7)) * 8;
    const int swB1 = ((cB + 1) ^ (srB & 7)) * 8;

    const int quad = lane >> 4, fr = lane & 15;

    for (int rep = 0; rep < REP; ++rep) {
        // prefetch chunk 0 (each repeat)
        float4 pa0 = *(const float4*)&gA[0];
        float4 pa1 = *(const float4*)&gA[4];
        uint4  pbh0 = *(const uint4*)&gBh[0], pbh1 = *(const uint4*)&gBh[8];
        uint4  pbl0 = *(const uint4*)&gBl[0], pbl1 = *(const uint4*)&gBl[8];

        for (int k0 = 0; k0 < 512; k0 += 64) {
            float fa[8];
            *(float4*)&fa[0] = pa0; *(float4*)&fa[4] = pa1;
            union { uint4 v; unsigned short s[8]; } h0, l0;
            #pragma unroll
            for (int e = 0; e < 8; ++e) {
                const unsigned short hb = f2bf(fa[e]);
                h0.s[e] = hb; l0.s[e] = f2bf(fa[e] - bf2f(hb));
            }
            __syncthreads();
            *(uint4*)&As_h[srA * 64 + swA] = h0.v;
            *(uint4*)&As_l[srA * 64 + swA] = l0.v;
            *(uint4*)&Bs_h[srB * 64 + swB0] = pbh0; *(uint4*)&Bs_h[srB * 64 + swB1] = pbh1;
            *(uint4*)&Bs_l[srB * 64 + swB0] = pbl0; *(uint4*)&Bs_l[srB * 64 + swB1] = pbl1;
            __syncthreads();

            if (k0 + 64 < 512) {
                pa0 = *(const float4*)&gA[k0 + 64];
                pa1 = *(const float4*)&gA[k0 + 68];
                pbh0 = *(const uint4*)&gBh[k0 + 64]; pbh1 = *(const uint4*)&gBh[k0 + 72];
                pbl0 = *(const uint4*)&gBl[k0 + 64]; pbl1 = *(const uint4*)&gBl[k0 + 72];
            }

            #pragma unroll
            for (int ks = 0; ks < 2; ++ks) {
                const int cchunk = ks * 4 + quad;
                const int m = wm + fr;
                const bf16x8 afh = *(const bf16x8*)&As_h[m * 64 + ((cchunk ^ (m & 7)) * 8)];
                const bf16x8 afl = *(const bf16x8*)&As_l[m * 64 + ((cchunk ^ (m & 7)) * 8)];
                bf16x8 bfh[2], bfl[2];
                #pragma unroll
                for (int nt = 0; nt < 2; ++nt) {
                    const int n = wn + nt * 16 + fr;
                    bfh[nt] = *(const bf16x8*)&Bs_h[n * 64 + ((cchunk ^ (n & 7)) * 8)];
                    bfl[nt] = *(const bf16x8*)&Bs_l[n * 64 + ((cchunk ^ (n & 7)) * 8)];
                }
                #pragma unroll
                for (int nt = 0; nt < 2; ++nt) {
                    acc[nt] = __builtin_amdgcn_mfma_f32_16x16x32_bf16(afh, bfh[nt], acc[nt], 0, 0, 0);
                    acc[nt] = __builtin_amdgcn_mfma_f32_16x16x32_bf16(afh, bfl[nt], acc[nt], 0, 0, 0);
                    acc[nt] = __builtin_amdgcn_mfma_f32_16x16x32_bf16(afl, bfh[nt], acc[nt], 0, 0, 0);
                }
            }
        }
    }

    const float scale = 1.0f / (float)REP;
    #pragma unroll
    for (int nt = 0; nt < 2; ++nt) {
        const int colg = col0 + wn + nt * 16 + fr;
        const float b1v = b1[colg];
        #pragma unroll
        for (int i = 0; i < 4; ++i) {
            const int rowg = row0 + wm + quad * 4 + i;
            const float v = acc[nt][i] * scale;
            if (isK) {
                const float e = fexp2((v + b1v) * C2L2E);
                const float ep = __shfl_xor(e, 1, 64);
                unsigned pk = ((fr & 1) == 0) ? packbf(e, ep) : packbf(ep, e);
                const unsigned pk2 = __shfl_xor(pk, 2, 64);
                if ((fr & 3) == 0) {
                    const int kidx = rowg >> 3;
                    const int bb   = rowg & 7;
                    const int hq   = colg >> 2;
                    ektq[((size_t)bb * 128 + hq) * 256 + kidx] = make_uint2(pk, pk2);
                }
            } else {
                eq[(size_t)(rowg - 2048) * 512 + colg] = fexp2(v * C2L2E);
            }
        }
    }
}

// ---------------------------------------------------------------------------
// Kernel 2: scoreav (R12 structure); score phase repeated REP x with a
// rotated hq-visit order per repeat (distinct addresses -> no CSE/LICM);
// racc accumulated across repeats, scaled by 1/REP.
// ---------------------------------------------------------------------------
__global__ __launch_bounds__(512) void scoreav_kernel(
    const uint2* __restrict__ ektq, const float* __restrict__ eq,
    const float* __restrict__ W2, const float* __restrict__ b2,
    const int* __restrict__ mask, const unsigned int* __restrict__ ckp,
    float* __restrict__ prob_out, float* __restrict__ out_ant)
{
    const int t    = threadIdx.x;
    const int lane = t & 63;
    const int wave = __builtin_amdgcn_readfirstlane(t >> 6);
    const int kk   = t & 255;
    const int half = t >> 8;
    const int q0   = blockIdx.x * 2;
    const int b    = blockIdx.y;

    __shared__ float eq0s[512], eq1s[512], w2s[512];
    __shared__ float rp[2][512];
    __shared__ float ps[2][256];
    __shared__ float pacc[8][2][512];

    eq0s[t] = eq[((size_t)q0 * 8 + b) * 512 + t];
    eq1s[t] = eq[((size_t)(q0 + 1) * 8 + b) * 512 + t];
    w2s[t]  = W2[t];

    const float4 wA = *(const float4*)&W2[lane * 4];
    const float4 wB = *(const float4*)&W2[256 + lane * 4];
    float s2 = wA.x + wA.y + wA.z + wA.w + wB.x + wB.y + wB.z + wB.w;
    #pragma unroll
    for (int m = 32; m; m >>= 1) s2 += __shfl_xor(s2, m, 64);
    const float base = s2 + b2[0];
    __syncthreads();

    const uint2* __restrict__ ekb = ektq + (size_t)b * 128 * 256 + kk;
    float racc0 = 0.0f, racc1 = 0.0f;

    for (int rep = 0; rep < REP; ++rep) {
        const int rot = rep * 16;
        uint2 L[2][8];
        #pragma unroll
        for (int j = 0; j < 8; ++j)
            L[0][j] = ekb[(size_t)(half * 64 + ((j + rot) & 63)) * 256];

        for (int g = 0; g < 8; ++g) {
            const int cur = g & 1;
            if (g < 7) {
                #pragma unroll
                for (int j = 0; j < 8; ++j)
                    L[cur ^ 1][j] = ekb[(size_t)(half * 64 + (((g + 1) * 8 + j + rot) & 63)) * 256];
            }
            #pragma unroll
            for (int j = 0; j < 8; ++j) {
                const int hq = half * 64 + ((g * 8 + j + rot) & 63);
                const int h  = hq * 4;
                const float ek0 = __builtin_bit_cast(float, L[cur][j].x << 16);
                const float ek1 = __builtin_bit_cast(float, L[cur][j].x & 0xFFFF0000u);
                const float ek2 = __builtin_bit_cast(float, L[cur][j].y << 16);
                const float ek3 = __builtin_bit_cast(float, L[cur][j].y & 0xFFFF0000u);
                const float4 w  = *(const float4*)&w2s[h];
                const float4 e0 = *(const float4*)&eq0s[h];
                const float4 e1 = *(const float4*)&eq1s[h];
                {   // q0
                    const float a0 = fmaf(ek0, e0.x, 1.0f);
                    const float a1 = fmaf(ek1, e0.y, 1.0f);
                    const float a2 = fmaf(ek2, e0.z, 1.0f);
                    const float a3 = fmaf(ek3, e0.w, 1.0f);
                    const float d01 = a0 * a1, d23 = a2 * a3;
                    const float n01 = fmaf(w.x, a1, w.y * a0);
                    const float n23 = fmaf(w.z, a3, w.w * a2);
                    const float N = fmaf(n01, d23, n23 * d01);
                    racc0 = fmaf(N, frcp(d01 * d23), racc0);
                }
                {   // q1
                    const float a0 = fmaf(ek0, e1.x, 1.0f);
                    const float a1 = fmaf(ek1, e1.y, 1.0f);
                    const float a2 = fmaf(ek2, e1.z, 1.0f);
                    const float a3 = fmaf(ek3, e1.w, 1.0f);
                    const float d01 = a0 * a1, d23 = a2 * a3;
                    const float n01 = fmaf(w.x, a1, w.y * a0);
                    const float n23 = fmaf(w.z, a3, w.w * a2);
                    const float N = fmaf(n01, d23, n23 * d01);
                    racc1 = fmaf(N, frcp(d01 * d23), racc1);
                }
            }
        }
    }
    rp[0][t] = racc0 * (1.0f / (float)REP);
    rp[1][t] = racc1 * (1.0f / (float)REP);
    __syncthreads();

    if (t < 256) {
        const int msk = mask[t * 8 + b];
        float s0 = base - 2.0f * (rp[0][t] + rp[0][t + 256]);
        float s1 = base - 2.0f * (rp[1][t] + rp[1][t + 256]);
        if (msk) { s0 = -INFINITY; s1 = -INFINITY; }
        ps[0][t] = s0;
        ps[1][t] = s1;
    }
    __syncthreads();

    if (wave < 2) {
        float4 sv = *(const float4*)&ps[wave][lane * 4];
        float m = fmaxf(fmaxf(sv.x, sv.y), fmaxf(sv.z, sv.w));
        #pragma unroll
        for (int d = 32; d; d >>= 1) m = fmaxf(m, __shfl_xor(m, d, 64));
        float4 pv;
        pv.x = fexp2((sv.x - m) * L2E);
        pv.y = fexp2((sv.y - m) * L2E);
        pv.z = fexp2((sv.z - m) * L2E);
        pv.w = fexp2((sv.w - m) * L2E);
        float sum = pv.x + pv.y + pv.z + pv.w;
        #pragma unroll
        for (int d = 32; d; d >>= 1) sum += __shfl_xor(sum, d, 64);
        const float inv = frcp(sum);
        pv.x *= inv; pv.y *= inv; pv.z *= inv; pv.w *= inv;
        *(float4*)&ps[wave][lane * 4] = pv;
        const int qb_idx = (q0 + wave) * 8 + b;
        const int kbase = lane * 4;
        prob_out[(size_t)(kbase + 0) * 1024 + qb_idx] = pv.x;
        prob_out[(size_t)(kbase + 1) * 1024 + qb_idx] = pv.y;
        prob_out[(size_t)(kbase + 2) * 1024 + qb_idx] = pv.z;
        prob_out[(size_t)(kbase + 3) * 1024 + qb_idx] = pv.w;
    }
    __syncthreads();

    {
        const int h0 = lane * 8;
        float4 aL0 = {}, aH0 = {}, aL1 = {}, aH1 = {};
        const int kstart = wave * 32;
        #pragma unroll 4
        for (int ki = 0; ki < 32; ++ki) {
            const int k = kstart + ki;
            const uint4 U = *(const uint4*)&ckp[((size_t)b * 256 + k) * 256 + lane * 4];
            float4 c0, c1;
            c0.x = __builtin_bit_cast(float, U.x << 16);
            c0.y = __builtin_bit_cast(float, U.x & 0xFFFF0000u);
            c0.z = __builtin_bit_cast(float, U.y << 16);
            c0.w = __builtin_bit_cast(float, U.y & 0xFFFF0000u);
            c1.x = __builtin_bit_cast(float, U.z << 16);
            c1.y = __builtin_bit_cast(float, U.z & 0xFFFF0000u);
            c1.z = __builtin_bit_cast(float, U.w << 16);
            c1.w = __builtin_bit_cast(float, U.w & 0xFFFF0000u);
            const float p0 = ps[0][k];
            const float p1 = ps[1][k];
            aL0.x = fmaf(p0, c0.x, aL0.x); aL0.y = fmaf(p0, c0.y, aL0.y);
            aL0.z = fmaf(p0, c0.z, aL0.z); aL0.w = fmaf(p0, c0.w, aL0.w);
            aH0.x = fmaf(p0, c1.x, aH0.x); aH0.y = fmaf(p0, c1.y, aH0.y);
            aH0.z = fmaf(p0, c1.z, aH0.z); aH0.w = fmaf(p0, c1.w, aH0.w);
            aL1.x = fmaf(p1, c0.x, aL1.x); aL1.y = fmaf(p1, c0.y, aL1.y);
            aL1.z = fmaf(p1, c0.z, aL1.z); aL1.w = fmaf(p1, c0.w, aL1.w);
            aH1.x = fmaf(p1, c1.x, aH1.x); aH1.y = fmaf(p1, c1.y, aH1.y);
            aH1.z = fmaf(p1, c1.z, aH1.z); aH1.w = fmaf(p1, c1.w, aH1.w);
        }
        *(float4*)&pacc[wave][0][h0 + 0] = aL0;
        *(float4*)&pacc[wave][0][h0 + 4] = aH0;
        *(float4*)&pacc[wave][1][h0 + 0] = aL1;
        *(float4*)&pacc[wave][1][h0 + 4] = aH1;
    }
    __syncthreads();

    {
        #pragma unroll
        for (int qi = 0; qi < 2; ++qi) {
            float s = 0.f;
            #pragma unroll
            for (int w = 0; w < 8; ++w) s += pacc[w][qi][t];
            out_ant[((size_t)(q0 + qi) * 8 + b) * 512 + t] = s;
        }
    }
}

// ---------------------------------------------------------------------------
extern "C" void kernel_launch(void* const* d_in, const int* in_sizes, int n_in,
                              void* d_out, int out_size, void* d_ws, size_t ws_size,
                              hipStream_t stream)
{
    const float* qry  = (const float*)d_in[0];
    const float* ckey = (const float*)d_in[1];
    const int*   mask = (const int*)d_in[2];
    const float* W1   = (const float*)d_in[3];
    const float* b1   = (const float*)d_in[4];
    const float* W2   = (const float*)d_in[5];
    const float* b2   = (const float*)d_in[6];

    float* out_ant  = (float*)d_out;
    float* out_prob = (float*)d_out + T_Q * BB * NHID;

    float* ws = (float*)d_ws;
    uint2* ws_ektq = (uint2*)ws;                              // 2MB
    float* ws_eq  = ws + 524288;                              // 2MB
    unsigned short* bt_hi = (unsigned short*)(ws + 1048576);  // 1MB
    unsigned short* bt_lo = (unsigned short*)(ws + 1310720);  // 1MB
    unsigned int* ws_ckp  = (unsigned int*)(ws + 1572864);    // 2MB

    convert_kernel<<<dim3(384), 256, 0, stream>>>(W1, ckey, bt_hi, bt_lo, ws_ckp);
    proj_kernel<<<dim3(96, 8), 256, 0, stream>>>(qry, ckey, bt_hi, bt_lo, b1, ws_ektq, ws_eq);
    scoreav_kernel<<<dim3(64, 8), 512, 0, stream>>>(ws_ektq, ws_eq, W2, b2, mask, ws_ckp,
                                                    out_prob, out_ant);
}

// Round 14
// 111.395 us; speedup vs baseline: 1.7576x; 1.7576x over previous
//
#include <hip/hip_runtime.h>
#include <math.h>

#define NHID 512
#define T_K  256
#define T_Q  128
#define BB   8

// tanh(x) = 1 - 2/(exp2(C*x)+1), C = 2*log2(e)
constexpr float C2L2E = 2.8853900817779268f;
constexpr float L2E   = 1.4426950408889634f;

__device__ __forceinline__ float fexp2(float x) { return __builtin_amdgcn_exp2f(x); }
__device__ __forceinline__ float frcp(float x)  { return __builtin_amdgcn_rcpf(x); }

typedef __attribute__((ext_vector_type(8))) short bf16x8;
typedef __attribute__((ext_vector_type(4))) float f32x4;

__device__ __forceinline__ unsigned short f2bf(float x) {
    unsigned u = __builtin_bit_cast(unsigned, x);
    unsigned r = (u + 0x7FFFu + ((u >> 16) & 1u)) >> 16;
    return (unsigned short)r;
}
__device__ __forceinline__ float bf2f(unsigned short h) {
    unsigned u = ((unsigned)h) << 16;
    return __builtin_bit_cast(float, u);
}
__device__ __forceinline__ unsigned packbf(float a, float b) {
    return (unsigned)f2bf(a) | ((unsigned)f2bf(b) << 16);
}
__device__ __forceinline__ float lo16(unsigned u) {
    return __builtin_bit_cast(float, u << 16);
}
__device__ __forceinline__ float hi16(unsigned u) {
    return __builtin_bit_cast(float, u & 0xFFFF0000u);
}

// ---------------------------------------------------------------------------
// Kernel 0: blocks 0..127: W1 -> BT_hi/lo. blocks 128..383: ckey -> ckp.
// ---------------------------------------------------------------------------
__global__ __launch_bounds__(256) void convert_kernel(
    const float* __restrict__ W1, const float* __restrict__ ckey,
    unsigned short* __restrict__ bt_hi, unsigned short* __restrict__ bt_lo,
    unsigned int* __restrict__ ckp)
{
    const int bid = blockIdx.x;
    const int t   = threadIdx.x;
    if (bid < 128) {
        const int kt = bid & 15;
        const int nt = bid >> 4;
        __shared__ float tile[64][65];
        const int r  = t >> 2;
        const int c0 = (t & 3) * 16;
        const float* src = W1 + (size_t)(kt * 64 + r) * 512 + nt * 64 + c0;
        #pragma unroll
        for (int j = 0; j < 4; ++j) {
            const float4 v = *(const float4*)&src[j * 4];
            tile[r][c0 + j * 4 + 0] = v.x; tile[r][c0 + j * 4 + 1] = v.y;
            tile[r][c0 + j * 4 + 2] = v.z; tile[r][c0 + j * 4 + 3] = v.w;
        }
        __syncthreads();
        const size_t dst = (size_t)((kt >> 3) * 512 + nt * 64 + r) * 512
                         + (size_t)((kt & 7) * 64 + c0);
        #pragma unroll
        for (int j4 = 0; j4 < 4; ++j4) {
            ushort4 h, l;
            #pragma unroll
            for (int e = 0; e < 4; ++e) {
                const float x = tile[c0 + j4 * 4 + e][r];
                const unsigned short hb = f2bf(x);
                ((unsigned short*)&h)[e] = hb;
                ((unsigned short*)&l)[e] = f2bf(x - bf2f(hb));
            }
            *(ushort4*)&bt_hi[dst + j4 * 4] = h;
            *(ushort4*)&bt_lo[dst + j4 * 4] = l;
        }
    } else {
        const int cb = bid - 128;      // 0..255
        const int b  = cb >> 5;        // 0..7
        const int kt = cb & 31;        // 0..31
        const int kloc = t >> 5;       // 0..7
        const int g    = t & 31;       // 0..31
        const int k = kt * 8 + kloc;
        const float* src = ckey + ((size_t)k * 8 + b) * 512 + g * 16;
        const float4 v0 = *(const float4*)&src[0];
        const float4 v1 = *(const float4*)&src[4];
        const float4 v2 = *(const float4*)&src[8];
        const float4 v3 = *(const float4*)&src[12];
        uint4 o0, o1;
        o0.x = packbf(v0.x, v0.y); o0.y = packbf(v0.z, v0.w);
        o0.z = packbf(v1.x, v1.y); o0.w = packbf(v1.z, v1.w);
        o1.x = packbf(v2.x, v2.y); o1.y = packbf(v2.z, v2.w);
        o1.z = packbf(v3.x, v3.y); o1.w = packbf(v3.z, v3.w);
        unsigned int* dst = ckp + ((size_t)b * 256 + k) * 256 + g * 8;
        *(uint4*)&dst[0] = o0;
        *(uint4*)&dst[4] = o1;
    }
}

// ---------------------------------------------------------------------------
// Kernel 1: proj GEMM, split-bf16 MFMA, 32-row tiles (768 blocks = 3/CU),
// register-prefetched double buffer. (R12 structure, proven ~8 us)
// ---------------------------------------------------------------------------
__global__ __launch_bounds__(256) void proj_kernel(
    const float* __restrict__ qry, const float* __restrict__ ckey,
    const unsigned short* __restrict__ bt_hi, const unsigned short* __restrict__ bt_lo,
    const float* __restrict__ b1,
    uint2* __restrict__ ektq, float* __restrict__ eq)
{
    const int row0 = blockIdx.x * 32;
    const int col0 = blockIdx.y * 64;
    const bool isK = row0 < 2048;
    const int bhalf = isK ? 0 : 512;

    __shared__ __align__(16) unsigned short As_h[32 * 64];
    __shared__ __align__(16) unsigned short As_l[32 * 64];
    __shared__ __align__(16) unsigned short Bs_h[64 * 64];
    __shared__ __align__(16) unsigned short Bs_l[64 * 64];

    const int t    = threadIdx.x;
    const int wave = t >> 6;
    const int lane = t & 63;
    const int wm = (wave & 1) * 16;
    const int wn = (wave >> 1) * 32;

    f32x4 acc[2] = {};

    const int srA = t >> 3;
    const int scA = (t & 7) * 8;
    const float* gA = (isK ? ckey + (size_t)(row0 + srA) * 512
                           : qry  + (size_t)(row0 - 2048 + srA) * 512) + scA;
    const int swA = ((scA >> 3) ^ (srA & 7)) * 8;

    const int srB = t >> 2;
    const int scB = (t & 3) * 16;
    const unsigned short* gBh = bt_hi + (size_t)(bhalf + col0 + srB) * 512 + scB;
    const unsigned short* gBl = bt_lo + (size_t)(bhalf + col0 + srB) * 512 + scB;
    const int cB = scB >> 3;
    const int swB0 = ((cB + 0) ^ (srB & 7)) * 8;
    const int swB1 = ((cB + 1) ^ (srB & 7)) * 8;

    const int quad = lane >> 4, fr = lane & 15;

    float4 pa0 = *(const float4*)&gA[0];
    float4 pa1 = *(const float4*)&gA[4];
    uint4  pbh0 = *(const uint4*)&gBh[0], pbh1 = *(const uint4*)&gBh[8];
    uint4  pbl0 = *(const uint4*)&gBl[0], pbl1 = *(const uint4*)&gBl[8];

    for (int k0 = 0; k0 < 512; k0 += 64) {
        float fa[8];
        *(float4*)&fa[0] = pa0; *(float4*)&fa[4] = pa1;
        union { uint4 v; unsigned short s[8]; } h0, l0;
        #pragma unroll
        for (int e = 0; e < 8; ++e) {
            const unsigned short hb = f2bf(fa[e]);
            h0.s[e] = hb; l0.s[e] = f2bf(fa[e] - bf2f(hb));
        }
        __syncthreads();
        *(uint4*)&As_h[srA * 64 + swA] = h0.v;
        *(uint4*)&As_l[srA * 64 + swA] = l0.v;
        *(uint4*)&Bs_h[srB * 64 + swB0] = pbh0; *(uint4*)&Bs_h[srB * 64 + swB1] = pbh1;
        *(uint4*)&Bs_l[srB * 64 + swB0] = pbl0; *(uint4*)&Bs_l[srB * 64 + swB1] = pbl1;
        __syncthreads();

        if (k0 + 64 < 512) {
            pa0 = *(const float4*)&gA[k0 + 64];
            pa1 = *(const float4*)&gA[k0 + 68];
            pbh0 = *(const uint4*)&gBh[k0 + 64]; pbh1 = *(const uint4*)&gBh[k0 + 72];
            pbl0 = *(const uint4*)&gBl[k0 + 64]; pbl1 = *(const uint4*)&gBl[k0 + 72];
        }

        #pragma unroll
        for (int ks = 0; ks < 2; ++ks) {
            const int cchunk = ks * 4 + quad;
            const int m = wm + fr;
            const bf16x8 afh = *(const bf16x8*)&As_h[m * 64 + ((cchunk ^ (m & 7)) * 8)];
            const bf16x8 afl = *(const bf16x8*)&As_l[m * 64 + ((cchunk ^ (m & 7)) * 8)];
            bf16x8 bfh[2], bfl[2];
            #pragma unroll
            for (int nt = 0; nt < 2; ++nt) {
                const int n = wn + nt * 16 + fr;
                bfh[nt] = *(const bf16x8*)&Bs_h[n * 64 + ((cchunk ^ (n & 7)) * 8)];
                bfl[nt] = *(const bf16x8*)&Bs_l[n * 64 + ((cchunk ^ (n & 7)) * 8)];
            }
            #pragma unroll
            for (int nt = 0; nt < 2; ++nt) {
                acc[nt] = __builtin_amdgcn_mfma_f32_16x16x32_bf16(afh, bfh[nt], acc[nt], 0, 0, 0);
                acc[nt] = __builtin_amdgcn_mfma_f32_16x16x32_bf16(afh, bfl[nt], acc[nt], 0, 0, 0);
                acc[nt] = __builtin_amdgcn_mfma_f32_16x16x32_bf16(afl, bfh[nt], acc[nt], 0, 0, 0);
            }
        }
    }

    #pragma unroll
    for (int nt = 0; nt < 2; ++nt) {
        const int colg = col0 + wn + nt * 16 + fr;
        const float b1v = b1[colg];
        #pragma unroll
        for (int i = 0; i < 4; ++i) {
            const int rowg = row0 + wm + quad * 4 + i;
            const float v = acc[nt][i];
            if (isK) {
                const float e = fexp2((v + b1v) * C2L2E);
                const float ep = __shfl_xor(e, 1, 64);
                unsigned pk = ((fr & 1) == 0) ? packbf(e, ep) : packbf(ep, e);
                const unsigned pk2 = __shfl_xor(pk, 2, 64);
                if ((fr & 3) == 0) {
                    const int kidx = rowg >> 3;
                    const int bb   = rowg & 7;
                    const int hq   = colg >> 2;
                    ektq[((size_t)bb * 128 + hq) * 256 + kidx] = make_uint2(pk, pk2);
                }
            } else {
                eq[(size_t)(rowg - 2048) * 512 + colg] = fexp2(v * C2L2E);
            }
        }
    }
}

// ---------------------------------------------------------------------------
// Kernel 2: fused score + softmax + antvec. 512 thr, grid (64,8).
// Score: thread=(k,h-half), double-buffered 8-load batches, FOUR fma chains
// (j-parity split per q) for 2x acc ILP (R13: VALUBusy 60% = latency gaps).
// Antvec: NO pacc LDS — wave owns 64 h, lane=(k-residue kq=l>>4, hq2=l&15),
// one uint2 per 4 h per k; combine k-residues via 2 shfl_xor steps;
// lanes 0-15 store q0, 16-31 store q1. LDS total 12 KB (was 44 KB).
// ---------------------------------------------------------------------------
__global__ __launch_bounds__(512) void scoreav_kernel(
    const uint2* __restrict__ ektq, const float* __restrict__ eq,
    const float* __restrict__ W2, const float* __restrict__ b2,
    const int* __restrict__ mask, const unsigned int* __restrict__ ckp,
    float* __restrict__ prob_out, float* __restrict__ out_ant)
{
    const int t    = threadIdx.x;
    const int lane = t & 63;
    const int wave = __builtin_amdgcn_readfirstlane(t >> 6);
    const int kk   = t & 255;
    const int half = t >> 8;
    const int q0   = blockIdx.x * 2;
    const int b    = blockIdx.y;

    __shared__ float eq0s[512], eq1s[512], w2s[512];   // 6 KB
    __shared__ float rp[2][512];                       // 4 KB
    __shared__ float ps[2][256];                       // 2 KB

    eq0s[t] = eq[((size_t)q0 * 8 + b) * 512 + t];
    eq1s[t] = eq[((size_t)(q0 + 1) * 8 + b) * 512 + t];
    w2s[t]  = W2[t];

    const float4 wA = *(const float4*)&W2[lane * 4];
    const float4 wB = *(const float4*)&W2[256 + lane * 4];
    float s2 = wA.x + wA.y + wA.z + wA.w + wB.x + wB.y + wB.z + wB.w;
    #pragma unroll
    for (int m = 32; m; m >>= 1) s2 += __shfl_xor(s2, m, 64);
    const float base = s2 + b2[0];
    __syncthreads();

    // ---- score: double-buffered batches, 4 accumulator chains ----
    const uint2* __restrict__ ekb = ektq + (size_t)b * 128 * 256 + kk;
    float r0a = 0.f, r0b = 0.f, r1a = 0.f, r1b = 0.f;

    uint2 L[2][8];
    #pragma unroll
    for (int j = 0; j < 8; ++j)
        L[0][j] = ekb[(size_t)(half * 64 + j) * 256];

    for (int g = 0; g < 8; ++g) {
        const int cur = g & 1;
        if (g < 7) {
            #pragma unroll
            for (int j = 0; j < 8; ++j)
                L[cur ^ 1][j] = ekb[(size_t)(half * 64 + (g + 1) * 8 + j) * 256];
        }
        #pragma unroll
        for (int j = 0; j < 8; ++j) {
            const int h = (half * 64 + g * 8 + j) * 4;
            const float ek0 = lo16(L[cur][j].x);
            const float ek1 = hi16(L[cur][j].x);
            const float ek2 = lo16(L[cur][j].y);
            const float ek3 = hi16(L[cur][j].y);
            const float4 w  = *(const float4*)&w2s[h];
            const float4 e0 = *(const float4*)&eq0s[h];
            const float4 e1 = *(const float4*)&eq1s[h];
            {   // q0
                const float a0 = fmaf(ek0, e0.x, 1.0f);
                const float a1 = fmaf(ek1, e0.y, 1.0f);
                const float a2 = fmaf(ek2, e0.z, 1.0f);
                const float a3 = fmaf(ek3, e0.w, 1.0f);
                const float d01 = a0 * a1, d23 = a2 * a3;
                const float n01 = fmaf(w.x, a1, w.y * a0);
                const float n23 = fmaf(w.z, a3, w.w * a2);
                const float N = fmaf(n01, d23, n23 * d01);
                if (j & 1) r0b = fmaf(N, frcp(d01 * d23), r0b);
                else       r0a = fmaf(N, frcp(d01 * d23), r0a);
            }
            {   // q1
                const float a0 = fmaf(ek0, e1.x, 1.0f);
                const float a1 = fmaf(ek1, e1.y, 1.0f);
                const float a2 = fmaf(ek2, e1.z, 1.0f);
                const float a3 = fmaf(ek3, e1.w, 1.0f);
                const float d01 = a0 * a1, d23 = a2 * a3;
                const float n01 = fmaf(w.x, a1, w.y * a0);
                const float n23 = fmaf(w.z, a3, w.w * a2);
                const float N = fmaf(n01, d23, n23 * d01);
                if (j & 1) r1b = fmaf(N, frcp(d01 * d23), r1b);
                else       r1a = fmaf(N, frcp(d01 * d23), r1a);
            }
        }
    }
    rp[0][t] = r0a + r0b;
    rp[1][t] = r1a + r1b;
    __syncthreads();

    if (t < 256) {
        const int msk = mask[t * 8 + b];
        float s0 = base - 2.0f * (rp[0][t] + rp[0][t + 256]);
        float s1 = base - 2.0f * (rp[1][t] + rp[1][t + 256]);
        if (msk) { s0 = -INFINITY; s1 = -INFINITY; }
        ps[0][t] = s0;
        ps[1][t] = s1;
    }
    __syncthreads();

    // ---- softmax: waves 0,1 ----
    if (wave < 2) {
        float4 sv = *(const float4*)&ps[wave][lane * 4];
        float m = fmaxf(fmaxf(sv.x, sv.y), fmaxf(sv.z, sv.w));
        #pragma unroll
        for (int d = 32; d; d >>= 1) m = fmaxf(m, __shfl_xor(m, d, 64));
        float4 pv;
        pv.x = fexp2((sv.x - m) * L2E);
        pv.y = fexp2((sv.y - m) * L2E);
        pv.z = fexp2((sv.z - m) * L2E);
        pv.w = fexp2((sv.w - m) * L2E);
        float sum = pv.x + pv.y + pv.z + pv.w;
        #pragma unroll
        for (int d = 32; d; d >>= 1) sum += __shfl_xor(sum, d, 64);
        const float inv = frcp(sum);
        pv.x *= inv; pv.y *= inv; pv.z *= inv; pv.w *= inv;
        *(float4*)&ps[wave][lane * 4] = pv;
        const int qb_idx = (q0 + wave) * 8 + b;
        const int kbase = lane * 4;
        prob_out[(size_t)(kbase + 0) * 1024 + qb_idx] = pv.x;
        prob_out[(size_t)(kbase + 1) * 1024 + qb_idx] = pv.y;
        prob_out[(size_t)(kbase + 2) * 1024 + qb_idx] = pv.z;
        prob_out[(size_t)(kbase + 3) * 1024 + qb_idx] = pv.w;
    }
    __syncthreads();

    // ---- antvec, pacc-free: only waves 0..7 of the k-dim are used via
    // wave -> h-range, lane -> (k-residue, h-quad) ----
    {
        const int kq  = lane >> 4;        // 0..3 (k residue mod 4)
        const int hq2 = lane & 15;        // 0..15 (h-quad within wave's 64 h)
        const int pbase = wave * 32 + hq2 * 2;   // bf16-pair index
        const unsigned int* __restrict__ ckb = ckp + (size_t)b * 256 * 256;
        float4 a0 = {}, a1 = {};
        #pragma unroll 8
        for (int ki = 0; ki < 64; ++ki) {
            const int k = ki * 4 + kq;
            const uint2 U = *(const uint2*)&ckb[(size_t)k * 256 + pbase];
            const float c0 = lo16(U.x), c1 = hi16(U.x);
            const float c2 = lo16(U.y), c3 = hi16(U.y);
            const float p0 = ps[0][k];
            const float p1 = ps[1][k];
            a0.x = fmaf(p0, c0, a0.x); a0.y = fmaf(p0, c1, a0.y);
            a0.z = fmaf(p0, c2, a0.z); a0.w = fmaf(p0, c3, a0.w);
            a1.x = fmaf(p1, c0, a1.x); a1.y = fmaf(p1, c1, a1.y);
            a1.z = fmaf(p1, c2, a1.z); a1.w = fmaf(p1, c3, a1.w);
        }
        // combine the 4 k-residues (lanes differing in bits 4,5)
        #pragma unroll
        for (int d = 16; d <= 32; d <<= 1) {
            a0.x += __shfl_xor(a0.x, d, 64); a0.y += __shfl_xor(a0.y, d, 64);
            a0.z += __shfl_xor(a0.z, d, 64); a0.w += __shfl_xor(a0.w, d, 64);
            a1.x += __shfl_xor(a1.x, d, 64); a1.y += __shfl_xor(a1.y, d, 64);
            a1.z += __shfl_xor(a1.z, d, 64); a1.w += __shfl_xor(a1.w, d, 64);
        }
        if (lane < 32) {
            const int qi = kq & 1;        // lanes 0-15 -> q0, 16-31 -> q1
            const int h0 = wave * 64 + hq2 * 4;
            const float4 outv = (qi == 0) ? a0 : a1;
            *(float4*)&out_ant[((size_t)(q0 + qi) * 8 + b) * 512 + h0] = outv;
        }
    }
}

// ---------------------------------------------------------------------------
extern "C" void kernel_launch(void* const* d_in, const int* in_sizes, int n_in,
                              void* d_out, int out_size, void* d_ws, size_t ws_size,
                              hipStream_t stream)
{
    const float* qry  = (const float*)d_in[0];
    const float* ckey = (const float*)d_in[1];
    const int*   mask = (const int*)d_in[2];
    const float* W1   = (const float*)d_in[3];
    const float* b1   = (const float*)d_in[4];
    const float* W2   = (const float*)d_in[5];
    const float* b2   = (const float*)d_in[6];

    float* out_ant  = (float*)d_out;
    float* out_prob = (float*)d_out + T_Q * BB * NHID;

    float* ws = (float*)d_ws;
    uint2* ws_ektq = (uint2*)ws;                              // 2MB
    float* ws_eq  = ws + 524288;                              // 2MB
    unsigned short* bt_hi = (unsigned short*)(ws + 1048576);  // 1MB
    unsigned short* bt_lo = (unsigned short*)(ws + 1310720);  // 1MB
    unsigned int* ws_ckp  = (unsigned int*)(ws + 1572864);    // 2MB

    convert_kernel<<<dim3(384), 256, 0, stream>>>(W1, ckey, bt_hi, bt_lo, ws_ckp);
    proj_kernel<<<dim3(96, 8), 256, 0, stream>>>(qry, ckey, bt_hi, bt_lo, b1, ws_ektq, ws_eq);
    scoreav_kernel<<<dim3(64, 8), 512, 0, stream>>>(ws_ektq, ws_eq, W2, b2, mask, ws_ckp,
                                                    out_prob, out_ant);
}